// Round 1
// baseline (4332.594 us; speedup 1.0000x reference)
//
#include <hip/hip_runtime.h>

typedef _Float16 f16;
typedef _Float16 half8 __attribute__((ext_vector_type(8)));
typedef _Float16 half2v __attribute__((ext_vector_type(2)));
typedef _Float16 half4 __attribute__((ext_vector_type(4)));
typedef float f32x4 __attribute__((ext_vector_type(4)));
typedef unsigned int uint2v __attribute__((ext_vector_type(2)));

#define G3 768

__global__ void cvt_f32_f16(const float* __restrict__ in, f16* __restrict__ out, int n) {
  int i = blockIdx.x * blockDim.x + threadIdx.x;
  if (i < n) out[i] = (f16)in[i];
}

// C[m][n] = sum_k A[m][k] * W[n][k] + b_ih[n] (+ b_hh[n] for n<512)
// Output written PRE-SWIZZLED for the scan kernel:
//   g = n>>8, u = n&255, ww = u>>5, lq = u&15, s = (u>>4)&1
//   g<2: GIri[(((m*8+ww)*16+lq)*4 + g*2 + s]   (f16)
//   g=2: GIn [(((m*8+ww)*16+lq)*2 + s]         (f16)
__global__ __launch_bounds__(256, 2)
void gi_gemm(const float* __restrict__ A, const f16* __restrict__ W,
             const float* __restrict__ b_ih, const float* __restrict__ b_hh,
             f16* __restrict__ GIri, f16* __restrict__ GIn) {
  const int tid = threadIdx.x;
  const int lane = tid & 63;
  const int w = tid >> 6;      // wave 0..3
  const int quad = lane >> 4;  // 0..3
  const int lq = lane & 15;
  const int m0 = blockIdx.x * 64;

  __shared__ __align__(16) f16 Al[64 * 264];
  __shared__ __align__(16) f16 Bl[48 * 264];

  // stage A tile: 64 rows x 256 f32 -> f16 LDS
#pragma unroll
  for (int i = 0; i < 16; ++i) {
    int f = i * 256 + tid;
    int row = f >> 6;
    int c4 = f & 63;
    float4 v = ((const float4*)A)[(size_t)(m0 + row) * 64 + c4];
    half4 hv = {(f16)v.x, (f16)v.y, (f16)v.z, (f16)v.w};
    *(half4*)&Al[row * 264 + c4 * 4] = hv;
  }
  __syncthreads();

  half8 af[8];
#pragma unroll
  for (int kc = 0; kc < 8; ++kc)
    af[kc] = *(half8*)&Al[(w * 16 + lq) * 264 + kc * 32 + quad * 8];

  for (int nc = 0; nc < 16; ++nc) {
    __syncthreads();
    int n0 = nc * 48;
#pragma unroll
    for (int i = 0; i < 6; ++i) {
      int f = i * 256 + tid;
      int row = f >> 5;
      int c8 = f & 31;
      half8 v = ((const half8*)(W + (size_t)(n0 + row) * 256))[c8];
      *(half8*)&Bl[row * 264 + c8 * 8] = v;
    }
    __syncthreads();

    f32x4 acc[3] = {};
#pragma unroll
    for (int kc = 0; kc < 8; ++kc) {
#pragma unroll
      for (int nt = 0; nt < 3; ++nt) {
        half8 bf = *(half8*)&Bl[(nt * 16 + lq) * 264 + kc * 32 + quad * 8];
        acc[nt] = __builtin_amdgcn_mfma_f32_16x16x32_f16(af[kc], bf, acc[nt], 0, 0, 0);
      }
    }
#pragma unroll
    for (int nt = 0; nt < 3; ++nt) {
      int n = n0 + nt * 16 + lq;
      float bv = b_ih[n] + (n < 512 ? b_hh[n] : 0.f);
      int g = n >> 8;
      int u = n & 255;
      int ww = u >> 5, lq16 = u & 15, s = (u >> 4) & 1;
#pragma unroll
      for (int r = 0; r < 4; ++r) {
        int m = m0 + w * 16 + quad * 4 + r;
        float val = acc[nt][r] + bv;
        size_t base = ((size_t)m * 8 + ww) * 16 + lq16;
        if (g < 2) GIri[base * 4 + g * 2 + s] = (f16)val;
        else       GIn[base * 2 + s] = (f16)val;
      }
    }
  }
}

__device__ __forceinline__ float sigf(float x) {
  return __builtin_amdgcn_rcpf(1.f + __expf(-x));
}
__device__ __forceinline__ float tanhf_(float x) {
  return 1.f - 2.f * __builtin_amdgcn_rcpf(__expf(2.f * x) + 1.f);
}

#define MF(af, bw, c) __builtin_amdgcn_mfma_f32_16x16x32_f16(af, bw, c, 0, 0, 0)

#define LOADW(t6, kc) { \
    const float* wr_ = Whh + (size_t)(((t6 >> 1) * 256) + w * 32 + ((t6 & 1) * 16) + lq) * 256 + (kc * 32 + colb); \
    float4 va_ = *(const float4*)wr_; float4 vb_ = *(const float4*)(wr_ + 4); \
    w##t6##kc = (half8){(f16)va_.x, (f16)va_.y, (f16)va_.z, (f16)va_.w, \
                        (f16)vb_.x, (f16)vb_.y, (f16)vb_.z, (f16)vb_.w}; }

#define LOADW_T6(t6) \
  LOADW(t6, 0) LOADW(t6, 1) LOADW(t6, 2) LOADW(t6, 3) \
  LOADW(t6, 4) LOADW(t6, 5) LOADW(t6, 6) LOADW(t6, 7)

#define UNPACK2(u32, lo, hi) { half2v h2_ = __builtin_bit_cast(half2v, (unsigned int)(u32)); \
                               lo = (float)h2_[0]; hi = (float)h2_[1]; }

// One step, restructured for issue density:
//   1. all 8 A-frag ds_read_b128 issued back-to-back at step start
//   2. gi unpack + distance-2 prefetch issued before the MFMA block
//   3. phase 1: r,i gates (a0..a3 round-robin, 32 MFMAs, same-acc distance 4)
//   4. phase 2: n gate with SPLIT accumulators (a4/a4b, a5/a5b over K-halves,
//      16 MFMAs, distance 4) -- the r/i sigmoids overlap phase-2 completion,
//      so the serial tail is only the tanh chain + write + barrier.
// Raw barrier (lgkm only; vmcnt stays outstanding so the distance-2 gi
// prefetch survives the barrier).
#define STEP(tcur, PRI, PN) { \
    const f16* hr_ = &hbuf[(tcur) & 1][0]; \
    half8 f0_ = *(const half8*)(hr_ + 0 * 32 + colb); \
    half8 f1_ = *(const half8*)(hr_ + 1 * 32 + colb); \
    half8 f2_ = *(const half8*)(hr_ + 2 * 32 + colb); \
    half8 f3_ = *(const half8*)(hr_ + 3 * 32 + colb); \
    half8 f4_ = *(const half8*)(hr_ + 4 * 32 + colb); \
    half8 f5_ = *(const half8*)(hr_ + 5 * 32 + colb); \
    half8 f6_ = *(const half8*)(hr_ + 6 * 32 + colb); \
    half8 f7_ = *(const half8*)(hr_ + 7 * 32 + colb); \
    float gr0_, gr1_, gi0_, gi1_, gn0_, gn1_; \
    UNPACK2(PRI[0], gr0_, gr1_); \
    UNPACK2(PRI[1], gi0_, gi1_); \
    UNPACK2(PN, gn0_, gn1_); \
    if ((tcur) + 2 < T) { \
      PRI = *(const uint2v*)(gri + (size_t)((tcur) + 2) * 512); \
      PN = *(const unsigned int*)(gn + (size_t)((tcur) + 2) * 256); \
    } \
    f32x4 a0 = {}, a1 = {}, a2 = {}, a3 = {}; \
    a0 = MF(f0_, w00, a0); a1 = MF(f0_, w10, a1); a2 = MF(f0_, w20, a2); a3 = MF(f0_, w30, a3); \
    a0 = MF(f1_, w01, a0); a1 = MF(f1_, w11, a1); a2 = MF(f1_, w21, a2); a3 = MF(f1_, w31, a3); \
    a0 = MF(f2_, w02, a0); a1 = MF(f2_, w12, a1); a2 = MF(f2_, w22, a2); a3 = MF(f2_, w32, a3); \
    a0 = MF(f3_, w03, a0); a1 = MF(f3_, w13, a1); a2 = MF(f3_, w23, a2); a3 = MF(f3_, w33, a3); \
    a0 = MF(f4_, w04, a0); a1 = MF(f4_, w14, a1); a2 = MF(f4_, w24, a2); a3 = MF(f4_, w34, a3); \
    a0 = MF(f5_, w05, a0); a1 = MF(f5_, w15, a1); a2 = MF(f5_, w25, a2); a3 = MF(f5_, w35, a3); \
    a0 = MF(f6_, w06, a0); a1 = MF(f6_, w16, a1); a2 = MF(f6_, w26, a2); a3 = MF(f6_, w36, a3); \
    a0 = MF(f7_, w07, a0); a1 = MF(f7_, w17, a1); a2 = MF(f7_, w27, a2); a3 = MF(f7_, w37, a3); \
    f32x4 a4 = {}, a5 = {}, a4b = {}, a5b = {}; \
    a4 = MF(f0_, w40, a4); a5 = MF(f0_, w50, a5); a4b = MF(f4_, w44, a4b); a5b = MF(f4_, w54, a5b); \
    a4 = MF(f1_, w41, a4); a5 = MF(f1_, w51, a5); a4b = MF(f5_, w45, a4b); a5b = MF(f5_, w55, a5b); \
    a4 = MF(f2_, w42, a4); a5 = MF(f2_, w52, a5); a4b = MF(f6_, w46, a4b); a5b = MF(f6_, w56, a5b); \
    a4 = MF(f3_, w43, a4); a5 = MF(f3_, w53, a5); a4b = MF(f7_, w47, a4b); a5b = MF(f7_, w57, a5b); \
    float rg0_ = sigf(gr0_ + a0[0]); \
    float rg1_ = sigf(gr1_ + a1[0]); \
    float ig0_ = sigf(gi0_ + a2[0]); \
    float ig1_ = sigf(gi1_ + a3[0]); \
    float ng0_ = tanhf_(gn0_ + rg0_ * (bn0 + a4[0] + a4b[0])); \
    float ng1_ = tanhf_(gn1_ + rg1_ * (bn1 + a5[0] + a5b[0])); \
    float hy0_ = ng0_ + ig0_ * (h0 - ng0_); \
    float hy1_ = ng1_ + ig1_ * (h1 - ng1_); \
    if (IS_KEY) { \
      if (quad == 0) { float* o_ = out + ((size_t)(tcur) * nb + b) * 256 + u0; o_[0] = rg0_; o_[16] = rg1_; } \
      h0 = hy0_; h1 = hy1_; \
    } else { \
      if (quad == 0) { float* o_ = out + ((size_t)(tcur) * nb + b) * 256 + u0; o_[0] = hy0_; o_[16] = hy1_; } \
      float gm0_ = 1.f, gm1_ = 1.f; \
      if ((tcur) < 16) { gm0_ = gates[(tcur) * 256 + u0]; gm1_ = gates[(tcur) * 256 + u0 + 16]; } \
      h0 = hy0_ * gm0_; h1 = hy1_ * gm1_; \
    } \
    if (quad == 0) { f16* hw_ = &hbuf[((tcur) + 1) & 1][0]; hw_[u0] = (f16)h0; hw_[u0 + 16] = (f16)h1; } \
    __asm__ volatile("" ::: "memory"); \
    __builtin_amdgcn_s_waitcnt(0xC07F); /* lgkmcnt(0), vmcnt/expcnt unconstrained */ \
    __builtin_amdgcn_s_barrier(); \
    __asm__ volatile("" ::: "memory"); }

// One block per chain, 512 threads (8 waves). W_hh resident in 48 named half8
// B-fragments per wave (192 VGPRs): wave w owns units [w*32, w*32+32), rows
// gate-grouped (t6 0,1 = r; 2,3 = i; 4,5 = n). A operand = h replicated in all
// 16 rows -> D cols = gh, identical in every reg/quad.
template <bool IS_KEY>
__global__ __launch_bounds__(512)
__attribute__((amdgpu_waves_per_eu(2, 2)))
void gru_scan(const float* __restrict__ Whh, const float* __restrict__ bhh,
              const f16* __restrict__ GIri, const f16* __restrict__ GIn,
              const float* __restrict__ gates, float* __restrict__ out, int T) {
  const int tid = threadIdx.x;
  const int lane = tid & 63;
  const int w = tid >> 6;      // 0..7
  const int quad = lane >> 4;  // 0..3
  const int lq = lane & 15;
  const int b = blockIdx.x;
  const int nb = gridDim.x;
  const int colb = quad * 8;
  const int u0 = w * 32 + lq;  // this lane's unit (s=0); s=1 -> u0+16

  __shared__ __align__(16) f16 hbuf[2][256];

  half8 w00, w01, w02, w03, w04, w05, w06, w07;
  half8 w10, w11, w12, w13, w14, w15, w16, w17;
  half8 w20, w21, w22, w23, w24, w25, w26, w27;
  half8 w30, w31, w32, w33, w34, w35, w36, w37;
  half8 w40, w41, w42, w43, w44, w45, w46, w47;
  half8 w50, w51, w52, w53, w54, w55, w56, w57;
  LOADW_T6(0) LOADW_T6(1) LOADW_T6(2) LOADW_T6(3) LOADW_T6(4) LOADW_T6(5)

  if (tid < 256) { hbuf[0][tid] = (f16)0.f; hbuf[1][tid] = (f16)0.f; }

  float h0 = 0.f, h1 = 0.f;
  const float bn0 = bhh[512 + u0];
  const float bn1 = bhh[512 + u0 + 16];

  const size_t mstart = (size_t)b * T;
  const f16* gri = GIri + ((mstart * 8 + w) * 16 + lq) * 4;  // +512 per step
  const f16* gn  = GIn + ((mstart * 8 + w) * 16 + lq) * 2;   // +256 per step

  uint2v priA = *(const uint2v*)(gri);
  unsigned int pnA = *(const unsigned int*)(gn);
  uint2v priB = *(const uint2v*)(gri + 512);
  unsigned int pnB = *(const unsigned int*)(gn + 256);

  __syncthreads();

  for (int t = 0; t < T; t += 2) {
    STEP(t, priA, pnA)
    STEP(t + 1, priB, pnB)
  }
}

__global__ void gate_mean(const float* __restrict__ rg, float* __restrict__ g) {
  int i = blockIdx.x * 256 + threadIdx.x;  // 16*256
  int l = i >> 8;
  int j = i & 255;
  float s = 0.f;
#pragma unroll
  for (int kb = 0; kb < 4; ++kb) s += rg[((size_t)l * 4 + kb) * 256 + j];
  g[i] = 0.25f * s;
}

extern "C" void kernel_launch(void* const* d_in, const int* in_sizes, int n_in,
                              void* d_out, int out_size, void* d_ws, size_t ws_size,
                              hipStream_t stream) {
  const float* x      = (const float*)d_in[0];  // [64][2048][256]
  const float* wm_key = (const float*)d_in[1];  // [4][16][256]
  const float* w_ih   = (const float*)d_in[2];  // [768][256]
  const float* w_hh   = (const float*)d_in[3];  // [768][256]
  const float* b_ih   = (const float*)d_in[4];  // [768]
  const float* b_hh   = (const float*)d_in[5];  // [768]
  float* out = (float*)d_out;                   // [2048][64][256]

  char* ws = (char*)d_ws;
  const size_t GIRI_OFF  = 0;                          // 131072*512*2 = 134217728
  const size_t GIN_OFF   = GIRI_OFF + 134217728ull;    // 131072*256*2 = 67108864
  const size_t WIH_OFF   = GIN_OFF + 67108864ull;      // 768*256*2 = 393216
  const size_t GIKRI_OFF = WIH_OFF + 393216ull;        // 64*512*2 = 65536
  const size_t GIKN_OFF  = GIKRI_OFF + 65536ull;       // 64*256*2 = 32768
  const size_t RG_OFF    = GIKN_OFF + 32768ull;        // 16*4*256*4 = 65536
  const size_t G_OFF     = RG_OFF + 65536ull;          // 16*256*4 = 16384
  f16*   GIri  = (f16*)(ws + GIRI_OFF);
  f16*   GIn   = (f16*)(ws + GIN_OFF);
  f16*   Wih   = (f16*)(ws + WIH_OFF);
  f16*   GIkri = (f16*)(ws + GIKRI_OFF);
  f16*   GIkn  = (f16*)(ws + GIKN_OFF);
  float* rg    = (float*)(ws + RG_OFF);
  float* g     = (float*)(ws + G_OFF);

  cvt_f32_f16<<<dim3(768), dim3(256), 0, stream>>>(w_ih, Wih, G3 * 256);
  gi_gemm<<<dim3(2048), dim3(256), 0, stream>>>(x, Wih, b_ih, b_hh, GIri, GIn);
  gi_gemm<<<dim3(1), dim3(256), 0, stream>>>(wm_key, Wih, b_ih, b_hh, GIkri, GIkn);
  gru_scan<true><<<dim3(4), dim3(512), 0, stream>>>(w_hh, b_hh, GIkri, GIkn, g, rg, 16);
  gate_mean<<<dim3(16), dim3(256), 0, stream>>>(rg, g);
  gru_scan<false><<<dim3(64), dim3(512), 0, stream>>>(w_hh, b_hh, GIri, GIn, g, out, 2048);
}

// Round 2
// 3130.854 us; speedup vs baseline: 1.3838x; 1.3838x over previous
//
#include <hip/hip_runtime.h>

typedef _Float16 f16;
typedef _Float16 half8 __attribute__((ext_vector_type(8)));
typedef _Float16 half2v __attribute__((ext_vector_type(2)));
typedef _Float16 half4 __attribute__((ext_vector_type(4)));
typedef float f32x4 __attribute__((ext_vector_type(4)));
typedef unsigned int uint2v __attribute__((ext_vector_type(2)));

#define G3 768

__global__ void cvt_f32_f16(const float* __restrict__ in, f16* __restrict__ out, int n) {
  int i = blockIdx.x * blockDim.x + threadIdx.x;
  if (i < n) out[i] = (f16)in[i];
}

// C[m][n] = sum_k A[m][k] * W[n][k] + b_ih[n] (+ b_hh[n] for n<512)
// Output written PRE-SWIZZLED for the scan kernel:
//   g = n>>8, u = n&255, ww = u>>5, lq = u&15, s = (u>>4)&1
//   g<2: GIri[(((m*8+ww)*16+lq)*4 + g*2 + s]   (f16)
//   g=2: GIn [(((m*8+ww)*16+lq)*2 + s]         (f16)
__global__ __launch_bounds__(256, 2)
void gi_gemm(const float* __restrict__ A, const f16* __restrict__ W,
             const float* __restrict__ b_ih, const float* __restrict__ b_hh,
             f16* __restrict__ GIri, f16* __restrict__ GIn) {
  const int tid = threadIdx.x;
  const int lane = tid & 63;
  const int w = tid >> 6;      // wave 0..3
  const int quad = lane >> 4;  // 0..3
  const int lq = lane & 15;
  const int m0 = blockIdx.x * 64;

  __shared__ __align__(16) f16 Al[64 * 264];
  __shared__ __align__(16) f16 Bl[48 * 264];

  // stage A tile: 64 rows x 256 f32 -> f16 LDS
#pragma unroll
  for (int i = 0; i < 16; ++i) {
    int f = i * 256 + tid;
    int row = f >> 6;
    int c4 = f & 63;
    float4 v = ((const float4*)A)[(size_t)(m0 + row) * 64 + c4];
    half4 hv = {(f16)v.x, (f16)v.y, (f16)v.z, (f16)v.w};
    *(half4*)&Al[row * 264 + c4 * 4] = hv;
  }
  __syncthreads();

  half8 af[8];
#pragma unroll
  for (int kc = 0; kc < 8; ++kc)
    af[kc] = *(half8*)&Al[(w * 16 + lq) * 264 + kc * 32 + quad * 8];

  for (int nc = 0; nc < 16; ++nc) {
    __syncthreads();
    int n0 = nc * 48;
#pragma unroll
    for (int i = 0; i < 6; ++i) {
      int f = i * 256 + tid;
      int row = f >> 5;
      int c8 = f & 31;
      half8 v = ((const half8*)(W + (size_t)(n0 + row) * 256))[c8];
      *(half8*)&Bl[row * 264 + c8 * 8] = v;
    }
    __syncthreads();

    f32x4 acc[3] = {};
#pragma unroll
    for (int kc = 0; kc < 8; ++kc) {
#pragma unroll
      for (int nt = 0; nt < 3; ++nt) {
        half8 bf = *(half8*)&Bl[(nt * 16 + lq) * 264 + kc * 32 + quad * 8];
        acc[nt] = __builtin_amdgcn_mfma_f32_16x16x32_f16(af[kc], bf, acc[nt], 0, 0, 0);
      }
    }
#pragma unroll
    for (int nt = 0; nt < 3; ++nt) {
      int n = n0 + nt * 16 + lq;
      float bv = b_ih[n] + (n < 512 ? b_hh[n] : 0.f);
      int g = n >> 8;
      int u = n & 255;
      int ww = u >> 5, lq16 = u & 15, s = (u >> 4) & 1;
#pragma unroll
      for (int r = 0; r < 4; ++r) {
        int m = m0 + w * 16 + quad * 4 + r;
        float val = acc[nt][r] + bv;
        size_t base = ((size_t)m * 8 + ww) * 16 + lq16;
        if (g < 2) GIri[base * 4 + g * 2 + s] = (f16)val;
        else       GIn[base * 2 + s] = (f16)val;
      }
    }
  }
}

__device__ __forceinline__ float sigf(float x) {
  return __builtin_amdgcn_rcpf(1.f + __expf(-x));
}
__device__ __forceinline__ float tanhf_(float x) {
  return 1.f - 2.f * __builtin_amdgcn_rcpf(__expf(2.f * x) + 1.f);
}

// ---- dot2 primitive (f32 accumulate) ----
#if defined(__has_builtin)
#if __has_builtin(__builtin_amdgcn_fdot2)
#define FD(a, b, c) __builtin_amdgcn_fdot2(a, b, c, false)
#endif
#endif
#ifndef FD
#define FD(a, b, c) ((c) + (float)(a)[0] * (float)(b)[0] + (float)(a)[1] * (float)(b)[1])
#endif

#define UNPACK2(u32, lo, hi) { half2v h2_ = __builtin_bit_cast(half2v, (unsigned int)(u32)); \
                               lo = (float)h2_[0]; hi = (float)h2_[1]; }

// Weight load: 1 output row (gate g, unit u), this thread's K-chunk quad*64..+64,
// f32 -> 32 packed half2 in registers.
#define LW(arr, g, u) { \
    const float* p_ = Whh + ((size_t)(g) * 256 + (u)) * 256 + quad * 64; \
    _Pragma("unroll") \
    for (int c_ = 0; c_ < 16; ++c_) { \
      float4 v_ = ((const float4*)p_)[c_]; \
      arr[c_ * 2]     = (half2v){(f16)v_.x, (f16)v_.y}; \
      arr[c_ * 2 + 1] = (half2v){(f16)v_.z, (f16)v_.w}; \
    } }

// 6 dot2s sharing one h-pair (static j -> registers)
#define D6(h2, j) \
  ar0 = FD(h2, wr0[j], ar0); ar1 = FD(h2, wr1[j], ar1); \
  ai0 = FD(h2, wi0[j], ai0); ai1 = FD(h2, wi1[j], ai1); \
  an0 = FD(h2, wn0[j], an0); an1 = FD(h2, wn1[j], an1);

// One 8-half chunk of h (conflict-free broadcast read) + 24 dot2
#define DCHUNK(c) { \
    half8 hv_ = *(const half8*)(hr_ + (c) * 32 + colb); \
    { half2v h2_ = (half2v){hv_[0], hv_[1]}; D6(h2_, (c) * 4 + 0) } \
    { half2v h2_ = (half2v){hv_[2], hv_[3]}; D6(h2_, (c) * 4 + 1) } \
    { half2v h2_ = (half2v){hv_[4], hv_[5]}; D6(h2_, (c) * 4 + 2) } \
    { half2v h2_ = (half2v){hv_[6], hv_[7]}; D6(h2_, (c) * 4 + 3) } }

// cross-quad K-reduce: xor-16 (ds_swizzle, within 32-lane halves) then xor-32 (bpermute)
#define RED(x) { \
    int t_ = __builtin_amdgcn_ds_swizzle(__builtin_bit_cast(int, x), 0x401F); \
    x += __builtin_bit_cast(float, t_); \
    t_ = __builtin_amdgcn_ds_bpermute(pidx, __builtin_bit_cast(int, x)); \
    x += __builtin_bit_cast(float, t_); }

// One step: 8 broadcast ds_read_b128 of h, 192 v_dot2_f32_f16 (6 outputs x 64 K),
// cross-quad reduce, scalar epilogue identical to the MFMA version.
// Raw barrier (lgkm only; vmcnt stays outstanding so the distance-2 gi prefetch
// survives the barrier).
#define STEP(tcur, PRI, PN) { \
    const f16* hr_ = &hbuf[(tcur) & 1][0]; \
    float ar0 = 0.f, ar1 = 0.f, ai0 = 0.f, ai1 = 0.f, an0 = 0.f, an1 = 0.f; \
    DCHUNK(0) DCHUNK(1) DCHUNK(2) DCHUNK(3) \
    float gr0_, gr1_, gi0_, gi1_, gn0_, gn1_; \
    UNPACK2(PRI[0], gr0_, gr1_); \
    UNPACK2(PRI[1], gi0_, gi1_); \
    UNPACK2(PN, gn0_, gn1_); \
    if ((tcur) + 2 < T) { \
      PRI = *(const uint2v*)(gri + (size_t)((tcur) + 2) * 512); \
      PN = *(const unsigned int*)(gn + (size_t)((tcur) + 2) * 256); \
    } \
    DCHUNK(4) DCHUNK(5) DCHUNK(6) DCHUNK(7) \
    RED(ar0) RED(ar1) RED(an0) RED(an1) RED(ai0) RED(ai1) \
    float rg0_ = sigf(gr0_ + ar0); \
    float rg1_ = sigf(gr1_ + ar1); \
    float ig0_ = sigf(gi0_ + ai0); \
    float ig1_ = sigf(gi1_ + ai1); \
    float ng0_ = tanhf_(gn0_ + rg0_ * (bn0 + an0)); \
    float ng1_ = tanhf_(gn1_ + rg1_ * (bn1 + an1)); \
    float hy0_ = ng0_ + ig0_ * (h0 - ng0_); \
    float hy1_ = ng1_ + ig1_ * (h1 - ng1_); \
    if (IS_KEY) { \
      if (quad == 0) { float* o_ = out + ((size_t)(tcur) * nb + b) * 256 + u0; o_[0] = rg0_; o_[16] = rg1_; } \
      h0 = hy0_; h1 = hy1_; \
    } else { \
      if (quad == 0) { float* o_ = out + ((size_t)(tcur) * nb + b) * 256 + u0; o_[0] = hy0_; o_[16] = hy1_; } \
      float gm0_ = 1.f, gm1_ = 1.f; \
      if ((tcur) < 16) { gm0_ = gates[(tcur) * 256 + u0]; gm1_ = gates[(tcur) * 256 + u0 + 16]; } \
      h0 = hy0_ * gm0_; h1 = hy1_ * gm1_; \
    } \
    if (quad == 0) { f16* hw_ = &hbuf[((tcur) + 1) & 1][0]; hw_[wa0] = (f16)h0; hw_[wa1] = (f16)h1; } \
    __asm__ volatile("" ::: "memory"); \
    __builtin_amdgcn_s_waitcnt(0xC07F); /* lgkmcnt(0), vmcnt/expcnt unconstrained */ \
    __builtin_amdgcn_s_barrier(); \
    __asm__ volatile("" ::: "memory"); }

// One block per chain, 512 threads (8 waves). VALU matvec: thread (w,quad,lq)
// owns outputs {r,i,n} x {u0, u0+16} (u0 = w*32+lq) for K-chunk quad*64..+64;
// weights resident as 6x32 half2 (192 VGPRs). h lives in LDS in an interleaved
// layout so the 4 quad-segments read from disjoint banks:
//   h[u] at f16-index ((u&63)>>3)*32 + (u>>6)*8 + (u&7)
// -> thread reads 8x ds_read_b128 at (c*32 + quad*8), same addr within each
// 16-lane group (broadcast), banks 16c+4q (conflict-free).
template <bool IS_KEY>
__global__ __launch_bounds__(512)
__attribute__((amdgpu_waves_per_eu(2, 2)))
void gru_scan(const float* __restrict__ Whh, const float* __restrict__ bhh,
              const f16* __restrict__ GIri, const f16* __restrict__ GIn,
              const float* __restrict__ gates, float* __restrict__ out, int T) {
  const int tid = threadIdx.x;
  const int lane = tid & 63;
  const int w = tid >> 6;      // 0..7
  const int quad = lane >> 4;  // 0..3
  const int lq = lane & 15;
  const int b = blockIdx.x;
  const int nb = gridDim.x;
  const int colb = quad * 8;
  const int u0 = w * 32 + lq;  // this lane's unit (s=0); s=1 -> u0+16
  const int pidx = (lane ^ 32) << 2;  // bpermute byte index for xor-32

  __shared__ __align__(16) f16 hbuf[2][256];

  // h-write indices in the interleaved layout (quad0 lanes write)
  const int u1 = u0 + 16;
  const int wa0 = ((u0 & 63) >> 3) * 32 + (u0 >> 6) * 8 + (u0 & 7);
  const int wa1 = ((u1 & 63) >> 3) * 32 + (u1 >> 6) * 8 + (u1 & 7);

  half2v wr0[32], wr1[32], wi0[32], wi1[32], wn0[32], wn1[32];
  LW(wr0, 0, u0) LW(wr1, 0, u1)
  LW(wi0, 1, u0) LW(wi1, 1, u1)
  LW(wn0, 2, u0) LW(wn1, 2, u1)

  if (tid < 256) { ((f16*)hbuf)[tid] = (f16)0.f; ((f16*)hbuf)[256 + tid] = (f16)0.f; }

  float h0 = 0.f, h1 = 0.f;
  const float bn0 = bhh[512 + u0];
  const float bn1 = bhh[512 + u1];

  const size_t mstart = (size_t)b * T;
  const f16* gri = GIri + ((mstart * 8 + w) * 16 + lq) * 4;  // +512 per step
  const f16* gn  = GIn + ((mstart * 8 + w) * 16 + lq) * 2;   // +256 per step

  uint2v priA = *(const uint2v*)(gri);
  unsigned int pnA = *(const unsigned int*)(gn);
  uint2v priB = *(const uint2v*)(gri + 512);
  unsigned int pnB = *(const unsigned int*)(gn + 256);

  __syncthreads();

  for (int t = 0; t < T; t += 2) {
    STEP(t, priA, pnA)
    STEP(t + 1, priB, pnB)
  }
}

__global__ void gate_mean(const float* __restrict__ rg, float* __restrict__ g) {
  int i = blockIdx.x * 256 + threadIdx.x;  // 16*256
  int l = i >> 8;
  int j = i & 255;
  float s = 0.f;
#pragma unroll
  for (int kb = 0; kb < 4; ++kb) s += rg[((size_t)l * 4 + kb) * 256 + j];
  g[i] = 0.25f * s;
}

extern "C" void kernel_launch(void* const* d_in, const int* in_sizes, int n_in,
                              void* d_out, int out_size, void* d_ws, size_t ws_size,
                              hipStream_t stream) {
  const float* x      = (const float*)d_in[0];  // [64][2048][256]
  const float* wm_key = (const float*)d_in[1];  // [4][16][256]
  const float* w_ih   = (const float*)d_in[2];  // [768][256]
  const float* w_hh   = (const float*)d_in[3];  // [768][256]
  const float* b_ih   = (const float*)d_in[4];  // [768]
  const float* b_hh   = (const float*)d_in[5];  // [768]
  float* out = (float*)d_out;                   // [2048][64][256]

  char* ws = (char*)d_ws;
  const size_t GIRI_OFF  = 0;                          // 131072*512*2 = 134217728
  const size_t GIN_OFF   = GIRI_OFF + 134217728ull;    // 131072*256*2 = 67108864
  const size_t WIH_OFF   = GIN_OFF + 67108864ull;      // 768*256*2 = 393216
  const size_t GIKRI_OFF = WIH_OFF + 393216ull;        // 64*512*2 = 65536
  const size_t GIKN_OFF  = GIKRI_OFF + 65536ull;       // 64*256*2 = 32768
  const size_t RG_OFF    = GIKN_OFF + 32768ull;        // 16*4*256*4 = 65536
  const size_t G_OFF     = RG_OFF + 65536ull;          // 16*256*4 = 16384
  f16*   GIri  = (f16*)(ws + GIRI_OFF);
  f16*   GIn   = (f16*)(ws + GIN_OFF);
  f16*   Wih   = (f16*)(ws + WIH_OFF);
  f16*   GIkri = (f16*)(ws + GIKRI_OFF);
  f16*   GIkn  = (f16*)(ws + GIKN_OFF);
  float* rg    = (float*)(ws + RG_OFF);
  float* g     = (float*)(ws + G_OFF);

  cvt_f32_f16<<<dim3(768), dim3(256), 0, stream>>>(w_ih, Wih, G3 * 256);
  gi_gemm<<<dim3(2048), dim3(256), 0, stream>>>(x, Wih, b_ih, b_hh, GIri, GIn);
  gi_gemm<<<dim3(1), dim3(256), 0, stream>>>(wm_key, Wih, b_ih, b_hh, GIkri, GIkn);
  gru_scan<true><<<dim3(4), dim3(512), 0, stream>>>(w_hh, b_hh, GIkri, GIkn, g, rg, 16);
  gate_mean<<<dim3(16), dim3(256), 0, stream>>>(rg, g);
  gru_scan<false><<<dim3(64), dim3(512), 0, stream>>>(w_hh, b_hh, GIri, GIn, g, out, 2048);
}